// Round 6
// baseline (1484.979 us; speedup 1.0000x reference)
//
#include <hip/hip_runtime.h>

#define REP20(M) M(0) M(1) M(2) M(3) M(4) M(5) M(6) M(7) M(8) M(9) \
                 M(10) M(11) M(12) M(13) M(14) M(15) M(16) M(17) M(18) M(19)

__device__ __forceinline__ float rl(float x, int l) {
    return __int_as_float(__builtin_amdgcn_readlane(__float_as_int(x), l));
}
template <int C>
__device__ __forceinline__ float qperm(float x) {
    return __int_as_float(__builtin_amdgcn_mov_dpp(__float_as_int(x), C, 0xF, 0xF, false));
}
__device__ __forceinline__ float rcp_(float x) { return __builtin_amdgcn_rcpf(x); }
__device__ __forceinline__ float sigmf(float a) { return rcp_(1.0f + __expf(-a)); }
__device__ __forceinline__ float tanh_(float a) {
    return fmaf(2.0f, rcp_(1.0f + __expf(-2.0f * a)) - 1.0f, 1.0f);
}
// m=1 -> sigmoid, m=2 -> tanh
__device__ __forceinline__ float actf(float a, float m) {
    float r = rcp_(1.0f + __expf(-m * a));
    return fmaf(m, r - 1.0f, 1.0f);
}

// dot over SGPR-held h-state (sh0..sh19), two interleaved chains
#define DOTS(P, R) { \
    float zE = P##0 * sh0,  zO = P##1 * sh1; \
    zE = fmaf(P##2,  sh2,  zE); zO = fmaf(P##3,  sh3,  zO); \
    zE = fmaf(P##4,  sh4,  zE); zO = fmaf(P##5,  sh5,  zO); \
    zE = fmaf(P##6,  sh6,  zE); zO = fmaf(P##7,  sh7,  zO); \
    zE = fmaf(P##8,  sh8,  zE); zO = fmaf(P##9,  sh9,  zO); \
    zE = fmaf(P##10, sh10, zE); zO = fmaf(P##11, sh11, zO); \
    zE = fmaf(P##12, sh12, zE); zO = fmaf(P##13, sh13, zO); \
    zE = fmaf(P##14, sh14, zE); zO = fmaf(P##15, sh15, zO); \
    zE = fmaf(P##16, sh16, zE); zO = fmaf(P##17, sh17, zO); \
    zE = fmaf(P##18, sh18, zE); zO = fmaf(P##19, sh19, zO); \
    R += zE + zO; }

// dot over VGPR c-state (cc0..cc19), two interleaved chains
#define DOTC(P, R) { \
    float zE = P##0 * cc0,  zO = P##1 * cc1; \
    zE = fmaf(P##2,  cc2,  zE); zO = fmaf(P##3,  cc3,  zO); \
    zE = fmaf(P##4,  cc4,  zE); zO = fmaf(P##5,  cc5,  zO); \
    zE = fmaf(P##6,  cc6,  zE); zO = fmaf(P##7,  cc7,  zO); \
    zE = fmaf(P##8,  cc8,  zE); zO = fmaf(P##9,  cc9,  zO); \
    zE = fmaf(P##10, cc10, zE); zO = fmaf(P##11, cc11, zO); \
    zE = fmaf(P##12, cc12, zE); zO = fmaf(P##13, cc13, zO); \
    zE = fmaf(P##14, cc14, zE); zO = fmaf(P##15, cc15, zO); \
    zE = fmaf(P##16, cc16, zE); zO = fmaf(P##17, cc17, zO); \
    zE = fmaf(P##18, cc18, zE); zO = fmaf(P##19, cc19, zO); \
    R += zE + zO; }

#define LOADC(BASE) { \
    const float4* q_ = (const float4*)(BASE); \
    float4 A4 = q_[0], B4 = q_[1], C4 = q_[2], D4 = q_[3], E4 = q_[4]; \
    cc0 = A4.x; cc1 = A4.y; cc2  = A4.z; cc3  = A4.w; \
    cc4 = B4.x; cc5 = B4.y; cc6  = B4.z; cc7  = B4.w; \
    cc8 = C4.x; cc9 = C4.y; cc10 = C4.z; cc11 = C4.w; \
    cc12 = D4.x; cc13 = D4.y; cc14 = D4.z; cc15 = D4.w; \
    cc16 = E4.x; cc17 = E4.y; cc18 = E4.z; cc19 = E4.w; }

#define RLH(k) sh##k = rl(hn, 2 * (k));

// layer-2 combine from actL (gates i,f,g,o on lanes 40..43), updates c2my/h2my
#define L2COMBINE(DEST_IDX_EXPR)  { \
    float i2 = qperm<0x00>(actL), f2 = qperm<0x55>(actL); \
    float g2 = qperm<0xAA>(actL), o2 = qperm<0xFF>(actL); \
    float c2n = fmaf(f2, c2my, i2 * g2); \
    h2my = o2 * tanh_(c2n); \
    c2my = c2n; \
    if (lane == 40) op[DEST_IDX_EXPR] = c2n; }

__global__ __launch_bounds__(64, 1)
void lstm2_kernel(const float* __restrict__ x_in,
                  const float* __restrict__ Wih1,
                  const float* __restrict__ Whh1,
                  const float* __restrict__ bih1,
                  const float* __restrict__ bhh1,
                  const float* __restrict__ Wih2,
                  const float* __restrict__ Whh2,
                  const float* __restrict__ bih2,
                  const float* __restrict__ bhh2,
                  float* __restrict__ out,
                  int T, int F)
{
    const int  lane = threadIdx.x;        // 1 wave = 1 batch chain
    const int  b    = blockIdx.x;
    const int  p    = lane & 1;
    int        j    = lane >> 1; if (j > 19) j = 19;
    const bool isL2 = (lane >= 40 && lane < 44);
    const int  g    = isL2 ? (lane - 40) : 0;

    // double-buffered c1 broadcast (only consumer: layer-2 dot, 1 step behind)
    __shared__ float sb[2][24];
    if (lane < 48) ((float*)sb)[lane] = 0.0f;
    __builtin_amdgcn_wave_barrier();

    // quad layout: lane 2j+0 -> rows (i_j, g_j); lane 2j+1 -> rows (f_j, o_j)
    const int rA = j + 20 * p;            // i / f
    const int rB = 40 + j + 20 * p;       // g / o

    const float* WArow = isL2 ? (Wih2 + g * 20) : (Whh1 + rA * 20);
    const float* WBrow = Whh1 + rB * 20;

#define LDW(k) float wA##k = WArow[k]; float wB##k = WBrow[k];
    REP20(LDW)
#undef LDW

    float wxA, wxB, bsA, bsB;
    {
        float u_wxA = Wih1[rA], u_wxB = Wih1[rB];
        float u_bsA = bih1[rA] + bhh1[rA];
        float u_bsB = bih1[rB] + bhh1[rB];
        float l_wxA = Whh2[g];            // multiplies h2 (O=1)
        float l_bsA = bih2[g] + bhh2[g];
        wxA = isL2 ? l_wxA : u_wxA;
        bsA = isL2 ? l_bsA : u_bsA;
        wxB = u_wxB;  bsB = u_bsB;
    }
    const float mB = p ? 1.0f : 2.0f;               // B row: g -> tanh, o -> sigm
    const float mL = (lane == 42) ? 2.0f : 1.0f;    // L2 'g' gate -> tanh

    // h-state in SGPRs (wave-uniform), c-state temporaries
#define DSH(k) float sh##k = 0.0f;
    REP20(DSH)
#undef DSH
    float cc0, cc1, cc2, cc3, cc4, cc5, cc6, cc7, cc8, cc9,
          cc10, cc11, cc12, cc13, cc14, cc15, cc16, cc17, cc18, cc19;

    float c1my = 0.0f, c2my = 0.0f, h2my = 0.0f;

    const float* xp = x_in + (long)b * T;
    float*       op = out  + (long)b * (T + F);

    float xr = xp[0];
    float x1 = xp[T > 1 ? 1 : 0];
    float x2 = xp[T > 2 ? 2 : 0];

    // ================= main scan: layer-2 runs 1 step behind =================
    for (int t = 0; t < T; ++t) {
        LOADC(sb[t & 1])                  // c1(t-1); latency hidden under layer-1
        int tn = t + 3; tn = (tn < T) ? tn : (T - 1);
        const float xf = xp[tn];

        // layer-1 gate dots over SGPR h-state  (L2 lanes: garbage, unused)
        float aA = fmaf(wxA, xr, bsA);
        float aB = fmaf(wxB, xr, bsB);
        DOTS(wA, aA)
        DOTS(wB, aB)
        // layer-2 gate dot over c1(t-1)       (main lanes: garbage, unused)
        float aL = fmaf(wxA, h2my, bsA);
        DOTC(wA, aL)

        float actA = sigmf(aA);           // i / f  (both sigmoid)
        float actB = actf(aB, mB);        // g(tanh) / o(sigm)
        float actL = actf(aL, mL);        // layer-2 own gate

        float nbA = qperm<0xB1>(actA);    // quad_perm [1,0,3,2]: partner's A
        float nbB = qperm<0xB1>(actB);
        float gi = p ? nbA : actA;
        float gf = p ? actA : nbA;
        float gg = p ? nbB : actB;
        float go = p ? actB : nbB;

        float cn = fmaf(gf, c1my, gi * gg);
        c1my = cn;
        if (!p && lane < 40) sb[(t & 1) ^ 1][j] = cn;   // publish c1(t) for L2
        float hn = go * tanh_(cn);

        REP20(RLH)                        // sh <- h1(t) via readlane (even lanes)

        if (t > 0) L2COMBINE(t - 1)       // layer-2 step t-1

        asm volatile("" ::: "memory");
        __builtin_amdgcn_wave_barrier();
        xr = x1; x1 = x2; x2 = xf;
    }

    // ================= drain: layer-2 step T-1 =================
    {
        LOADC(sb[T & 1])                  // c1(T-1)
        float aL = fmaf(wxA, h2my, bsA);
        DOTC(wA, aL)
        float actL = actf(aL, mL);
        L2COMBINE(T - 1)
    }
    float xF = rl(c2my, 40);

    // ================= future phase (F steps, serial) =================
    for (int i = 0; i < F; ++i) {
        float aA = fmaf(wxA, xF, bsA);
        float aB = fmaf(wxB, xF, bsB);
        DOTS(wA, aA)
        DOTS(wB, aB)
        float actA = sigmf(aA);
        float actB = actf(aB, mB);
        float nbA = qperm<0xB1>(actA);
        float nbB = qperm<0xB1>(actB);
        float gi = p ? nbA : actA;
        float gf = p ? actA : nbA;
        float gg = p ? nbB : actB;
        float go = p ? actB : nbB;
        float cn = fmaf(gf, c1my, gi * gg);
        c1my = cn;
        if (!p && lane < 40) sb[0][j] = cn;             // c1 of THIS step
        float hn = go * tanh_(cn);
        REP20(RLH)
        asm volatile("" ::: "memory");
        __builtin_amdgcn_wave_barrier();

        LOADC(sb[0])
        float aL = fmaf(wxA, h2my, bsA);
        DOTC(wA, aL)
        float actL = actf(aL, mL);
        L2COMBINE(T + i)
        xF = rl(c2my, 40);
        asm volatile("" ::: "memory");
        __builtin_amdgcn_wave_barrier();
    }
}

extern "C" void kernel_launch(void* const* d_in, const int* in_sizes, int n_in,
                              void* d_out, int out_size, void* d_ws, size_t ws_size,
                              hipStream_t stream) {
    const float* x    = (const float*)d_in[0];
    const float* Wih1 = (const float*)d_in[1];
    const float* Whh1 = (const float*)d_in[2];
    const float* bih1 = (const float*)d_in[3];
    const float* bhh1 = (const float*)d_in[4];
    const float* Wih2 = (const float*)d_in[5];
    const float* Whh2 = (const float*)d_in[6];
    const float* bih2 = (const float*)d_in[7];
    const float* bhh2 = (const float*)d_in[8];
    float* out = (float*)d_out;

    const int B = 1024;
    const int T = in_sizes[0] / B;        // 4096
    const int F = out_size / B - T;       // 16

    hipLaunchKernelGGL(lstm2_kernel, dim3(B), dim3(64), 0, stream,
                       x, Wih1, Whh1, bih1, bhh1, Wih2, Whh2, bih2, bhh2, out, T, F);
}